// Round 2
// baseline (303.341 us; speedup 1.0000x reference)
//
#include <hip/hip_runtime.h>
#include <stdint.h>
#include <stddef.h>

// GAT layer: B=2048, M=64, C=256, f32 in/out.
// h = x @ W^T ; s_i = h@a_i ; s_j = h@a_j ; e = lrelu(s_i+s_j, 0.2)
// attn = softmax_j(e) ; out = relu(attn @ h)
//
// Strategy: f16 hi/lo split (3-term) MFMA for both matmuls -> f32-class
// accuracy at matrix-core rate; fully fused one-block-per-batch kernel;
// 80KB LDS (2 blocks/CU). Memory-bound target ~42us floor (268MB @ 6.3TB/s).

#define NB 2048
#define MM 64
#define CC 256

typedef __attribute__((ext_vector_type(4))) float    f32x4;
typedef __attribute__((ext_vector_type(8))) _Float16 h16x8;
typedef __attribute__((ext_vector_type(4))) _Float16 h16x4;

// LDS layout (81920 B total):
//   [0      .. 32768)  x_hi  [64][256] f16, 512B rows, 16B-granule XOR swizzle (g ^ (r&7))
//                      ... later reused as hT_hi [256][64] f16, 128B rows, same swizzle
//   [32768  .. 65536)  x_lo / hT_lo (same layouts)
//   [65536  .. 73728)  attn_hi [64][64] f16 128B rows swizzled; start also overlays
//                      s_part (2KB) + s_final (512B), which die before attn is written
//   [73728  .. 81920)  attn_lo
#define XH 0
#define XL 32768
#define AT 65536
#define ATL 73728

__device__ __forceinline__ f32x4 mfma16(h16x8 a, h16x8 b, f32x4 c) {
    return __builtin_amdgcn_mfma_f32_16x16x32_f16(a, b, c, 0, 0, 0);
}

__global__ void prep_w(const float* __restrict__ W,
                       _Float16* __restrict__ Wh, _Float16* __restrict__ Wl) {
    int t = blockIdx.x * 256 + threadIdx.x;      // 16384 threads, 4 f32 each
    f32x4 v = ((const f32x4*)W)[t];
    h16x4 hv, lv;
#pragma unroll
    for (int e = 0; e < 4; ++e) {
        _Float16 h = (_Float16)v[e];
        hv[e] = h;
        lv[e] = (_Float16)(v[e] - (float)h);
    }
    ((h16x4*)Wh)[t] = hv;
    ((h16x4*)Wl)[t] = lv;
}

__global__ __launch_bounds__(256, 2)
void gat_kernel(const float* __restrict__ x, const float* __restrict__ aw,
                const _Float16* __restrict__ Wh, const _Float16* __restrict__ Wl,
                float* __restrict__ out) {
    extern __shared__ char smem[];
    const int b    = blockIdx.x;
    const int tid  = threadIdx.x;
    const int w    = tid >> 6;      // wave 0..3 (owns output-col slice w*64..w*64+63)
    const int lane = tid & 63;
    const int l15  = lane & 15;
    const int lq   = lane >> 4;

    // ---------------- stage x -> LDS as f16 hi/lo (swizzled) ----------------
    const float* xb = x + (size_t)b * (MM * CC);
#pragma unroll
    for (int it = 0; it < 8; ++it) {
        int r  = it * 8 + (tid >> 5);        // row 0..63
        int c8 = tid & 31;                   // 16B granule (8 f16) within row
        const float* src = xb + r * CC + c8 * 8;
        f32x4 v0 = *(const f32x4*)(src);
        f32x4 v1 = *(const f32x4*)(src + 4);
        h16x8 hv, lv;
#pragma unroll
        for (int e = 0; e < 4; ++e) {
            float f0 = v0[e], f1 = v1[e];
            _Float16 h0 = (_Float16)f0; hv[e]     = h0; lv[e]     = (_Float16)(f0 - (float)h0);
            _Float16 h1 = (_Float16)f1; hv[4 + e] = h1; lv[4 + e] = (_Float16)(f1 - (float)h1);
        }
        int byte = r * 512 + ((c8 ^ (r & 7)) * 16);
        *(h16x8*)(smem + XH + byte) = hv;
        *(h16x8*)(smem + XL + byte) = lv;
    }
    __syncthreads();

    // ---------------- matmul1: h = x @ W^T  (n-partitioned across waves) ----
    // wave w computes h[all 64 rows][cols w*64 .. w*64+63] as 4x4 MFMA tiles
    f32x4 acc[4][4] = {};
    {
        h16x8 Bh[2][4], Bl[2][4];
#pragma unroll
        for (int nt = 0; nt < 4; ++nt) {
            int col = w * 64 + nt * 16 + l15;       // W row (output channel o)
            Bh[0][nt] = *(const h16x8*)(Wh + col * CC + lq * 8);
            Bl[0][nt] = *(const h16x8*)(Wl + col * CC + lq * 8);
        }
#pragma unroll
        for (int ks = 0; ks < 8; ++ks) {
            int cur = ks & 1, nxt = cur ^ 1;
            if (ks < 7) {
#pragma unroll
                for (int nt = 0; nt < 4; ++nt) {
                    int col = w * 64 + nt * 16 + l15;
                    Bh[nxt][nt] = *(const h16x8*)(Wh + col * CC + (ks + 1) * 32 + lq * 8);
                    Bl[nxt][nt] = *(const h16x8*)(Wl + col * CC + (ks + 1) * 32 + lq * 8);
                }
            }
#pragma unroll
            for (int mt = 0; mt < 4; ++mt) {
                int r = mt * 16 + l15;
                int g = (((ks * 4 + lq) ^ (r & 7)) * 16);
                h16x8 Ah = *(const h16x8*)(smem + XH + r * 512 + g);
                h16x8 Al = *(const h16x8*)(smem + XL + r * 512 + g);
#pragma unroll
                for (int nt = 0; nt < 4; ++nt) {
                    acc[mt][nt] = mfma16(Al, Bh[cur][nt], acc[mt][nt]);
                    acc[mt][nt] = mfma16(Ah, Bl[cur][nt], acc[mt][nt]);
                    acc[mt][nt] = mfma16(Ah, Bh[cur][nt], acc[mt][nt]);
                }
            }
        }
    }

    // ---------------- s_i / s_j partials from accumulators ----------------
    float* sparti = (float*)(smem + AT);            // [4][64]
    float* spartj = (float*)(smem + AT + 1024);     // [4][64]
    float* sfini  = (float*)(smem + AT + 2048);     // [64]
    float* sfinj  = (float*)(smem + AT + 2304);     // [64]
    {
        float ai[4], aj[4];
#pragma unroll
        for (int nt = 0; nt < 4; ++nt) {
            int col = w * 64 + nt * 16 + l15;
            ai[nt] = aw[col];
            aj[nt] = aw[256 + col];
        }
#pragma unroll
        for (int mt = 0; mt < 4; ++mt) {
#pragma unroll
            for (int rg = 0; rg < 4; ++rg) {
                float s1 = 0.f, s2 = 0.f;
#pragma unroll
                for (int nt = 0; nt < 4; ++nt) {
                    float v = acc[mt][nt][rg];
                    s1 += v * ai[nt];
                    s2 += v * aj[nt];
                }
                s1 += __shfl_xor(s1, 1);  s2 += __shfl_xor(s2, 1);
                s1 += __shfl_xor(s1, 2);  s2 += __shfl_xor(s2, 2);
                s1 += __shfl_xor(s1, 4);  s2 += __shfl_xor(s2, 4);
                s1 += __shfl_xor(s1, 8);  s2 += __shfl_xor(s2, 8);
                if (l15 == 0) {
                    int row = mt * 16 + lq * 4 + rg;
                    sparti[w * 64 + row] = s1;
                    spartj[w * 64 + row] = s2;
                }
            }
        }
    }
    __syncthreads();   // all x-reads done; s partials visible

    // ---------------- write hT (hi/lo) over dead x buffer; reduce s --------
#pragma unroll
    for (int mt = 0; mt < 4; ++mt) {
#pragma unroll
        for (int nt = 0; nt < 4; ++nt) {
            h16x4 hh, ll;
#pragma unroll
            for (int rg = 0; rg < 4; ++rg) {
                float f = acc[mt][nt][rg];
                _Float16 h = (_Float16)f;
                hh[rg] = h;
                ll[rg] = (_Float16)(f - (float)h);
            }
            int c    = w * 64 + nt * 16 + l15;   // channel (hT row)
            int jb   = mt * 16 + lq * 4;         // node index (hT col base)
            int byte = c * 128 + (((jb >> 3) ^ (c & 7)) * 16) + (jb & 7) * 2;
            *(h16x4*)(smem + XH + byte) = hh;
            *(h16x4*)(smem + XL + byte) = ll;
        }
    }
    if (tid < 128) {
        int row = tid & 63;
        float* sp = (tid < 64) ? sparti : spartj;
        float v = sp[row] + sp[64 + row] + sp[128 + row] + sp[192 + row];
        ((tid < 64) ? sfini : sfinj)[row] = v;
    }
    __syncthreads();

    // ---------------- softmax over j (wave-parallel: lane -> row, lq -> j-chunk)
    {
        int i  = w * 16 + l15;      // row handled by this lane
        int jb = lq * 16;           // 16-j chunk
        float siv = sfini[i];
        float p[16];
        float mx = -1e30f;
#pragma unroll
        for (int t4 = 0; t4 < 4; ++t4) {
            f32x4 sv = *(const f32x4*)(sfinj + jb + t4 * 4);
#pragma unroll
            for (int e = 0; e < 4; ++e) {
                float ev = siv + sv[e];
                ev = ev > 0.f ? ev : 0.2f * ev;    // leaky_relu(0.2)
                p[t4 * 4 + e] = ev;
                mx = fmaxf(mx, ev);
            }
        }
        mx = fmaxf(mx, __shfl_xor(mx, 16));
        mx = fmaxf(mx, __shfl_xor(mx, 32));
        float sum = 0.f;
#pragma unroll
        for (int t = 0; t < 16; ++t) { p[t] = __expf(p[t] - mx); sum += p[t]; }
        sum += __shfl_xor(sum, 16);
        sum += __shfl_xor(sum, 32);
        float inv = 1.0f / sum;
        __syncthreads();   // everyone done reading s region before attn overwrites it
        h16x8 ph0, ph1, pl0, pl1;
#pragma unroll
        for (int t = 0; t < 8; ++t) {
            float f0 = p[t] * inv;     _Float16 h0 = (_Float16)f0;
            ph0[t] = h0; pl0[t] = (_Float16)(f0 - (float)h0);
            float f1 = p[8 + t] * inv; _Float16 h1 = (_Float16)f1;
            ph1[t] = h1; pl1[t] = (_Float16)(f1 - (float)h1);
        }
        int base = AT + i * 128;
        int g0 = (((2 * lq)     ^ (i & 7)) * 16);
        int g1 = (((2 * lq + 1) ^ (i & 7)) * 16);
        *(h16x8*)(smem + base + g0) = ph0;
        *(h16x8*)(smem + base + g1) = ph1;
        *(h16x8*)(smem + (ATL - AT) + base + g0) = pl0;
        *(h16x8*)(smem + (ATL - AT) + base + g1) = pl1;
    }
    __syncthreads();

    // ---------------- matmul2: out = relu(attn @ h), n-partitioned ---------
    f32x4 acc2[4][4] = {};
#pragma unroll
    for (int ks = 0; ks < 2; ++ks) {
        h16x8 Ah[4], Al[4], Bh2[4], Bl2[4];
#pragma unroll
        for (int mt = 0; mt < 4; ++mt) {
            int r = mt * 16 + l15;
            int g = (((ks * 4 + lq) ^ (r & 7)) * 16);
            Ah[mt] = *(const h16x8*)(smem + AT  + r * 128 + g);
            Al[mt] = *(const h16x8*)(smem + ATL + r * 128 + g);
        }
#pragma unroll
        for (int nt = 0; nt < 4; ++nt) {
            int c = w * 64 + nt * 16 + l15;
            int g = (((ks * 4 + lq) ^ (c & 7)) * 16);
            Bh2[nt] = *(const h16x8*)(smem + XH + c * 128 + g);
            Bl2[nt] = *(const h16x8*)(smem + XL + c * 128 + g);
        }
#pragma unroll
        for (int mt = 0; mt < 4; ++mt) {
#pragma unroll
            for (int nt = 0; nt < 4; ++nt) {
                acc2[mt][nt] = mfma16(Al[mt], Bh2[nt], acc2[mt][nt]);
                acc2[mt][nt] = mfma16(Ah[mt], Bl2[nt], acc2[mt][nt]);
                acc2[mt][nt] = mfma16(Ah[mt], Bh2[nt], acc2[mt][nt]);
            }
        }
    }

    // ---------------- relu + store --------------------------------------
    float* ob = out + (size_t)b * (MM * CC);
#pragma unroll
    for (int mt = 0; mt < 4; ++mt) {
#pragma unroll
        for (int nt = 0; nt < 4; ++nt) {
            int col = w * 64 + nt * 16 + l15;
#pragma unroll
            for (int rg = 0; rg < 4; ++rg) {
                int row = mt * 16 + lq * 4 + rg;
                ob[row * CC + col] = fmaxf(acc2[mt][nt][rg], 0.f);
            }
        }
    }
}

extern "C" void kernel_launch(void* const* d_in, const int* in_sizes, int n_in,
                              void* d_out, int out_size, void* d_ws, size_t ws_size,
                              hipStream_t stream) {
    (void)in_sizes; (void)n_in; (void)out_size; (void)ws_size;
    const float* x  = (const float*)d_in[0];
    const float* W  = (const float*)d_in[1];
    const float* aw = (const float*)d_in[2];
    float* out = (float*)d_out;

    _Float16* Wh = (_Float16*)d_ws;          // 65536 f16 = 128KB
    _Float16* Wl = Wh + 65536;               // another 128KB

    (void)hipFuncSetAttribute((const void*)gat_kernel,
                              hipFuncAttributeMaxDynamicSharedMemorySize, 81920);

    prep_w<<<64, 256, 0, stream>>>(W, Wh, Wl);
    gat_kernel<<<NB, 256, 81920, stream>>>(x, aw, Wh, Wl, out);
}

// Round 6
// 290.355 us; speedup vs baseline: 1.0447x; 1.0447x over previous
//
#include <hip/hip_runtime.h>
#include <stdint.h>
#include <stddef.h>

// GAT layer: B=2048, M=64, C=256, f32 in/out.
// h = x@W^T ; s_i=h@a_i ; s_j=h@a_j ; e=lrelu(s_i+s_j,0.2) ; attn=softmax_j(e)
// out = relu(attn @ h)
//
// R2 -> R3: occupancy fix. 512 thr / 8 waves per block (each wave a 64x32
// output slice, acc=32 regs), __launch_bounds__(512,4) => <=128 regs =>
// 16 waves/CU (was 8). Vectorized epilogue via LDS bounce. Same f16 hi/lo
// 3-term MFMA numerics (absmax 0.00195 passed).
// R3 -> R4: fix ternary-deref compile error. R4..R6: resubmits (infra timeouts).

#define NB 2048
#define MM 64
#define CC 256

typedef __attribute__((ext_vector_type(4))) float    f32x4;
typedef __attribute__((ext_vector_type(8))) _Float16 h16x8;
typedef __attribute__((ext_vector_type(4))) _Float16 h16x4;

// LDS (81920 B):
//   [0,32768)      x_hi [64][256] f16 rows 512B, granule^=(r&7) swizzle
//                  -> reused as hT_hi [256][64] f16 rows 128B, same swizzle
//   [32768,65536)  x_lo / hT_lo
//   [65536,73728)  s-buffers (die before attn written), then attn_hi [64][64]
//   [73728,81920)  attn_lo
//   epilogue: out staging f32 [64 rows][stride 1040B] over [0,66560)
#define XH  0
#define XL  32768
#define AT  65536
#define ATL 73728
#define SP_I 65536
#define SP_J 67584
#define SF_I 69632
#define SF_J 69888
#define OSTR 1040   // 260 f32; 16B-aligned rows; 2-way (free) write conflicts

__device__ __forceinline__ f32x4 mfma16(h16x8 a, h16x8 b, f32x4 c) {
    return __builtin_amdgcn_mfma_f32_16x16x32_f16(a, b, c, 0, 0, 0);
}

__global__ void prep_w(const float* __restrict__ W,
                       _Float16* __restrict__ Wh, _Float16* __restrict__ Wl) {
    int t = blockIdx.x * 256 + threadIdx.x;      // 16384 threads, 4 f32 each
    f32x4 v = ((const f32x4*)W)[t];
    h16x4 hv, lv;
#pragma unroll
    for (int e = 0; e < 4; ++e) {
        _Float16 h = (_Float16)v[e];
        hv[e] = h;
        lv[e] = (_Float16)(v[e] - (float)h);
    }
    ((h16x4*)Wh)[t] = hv;
    ((h16x4*)Wl)[t] = lv;
}

__global__ __launch_bounds__(512, 4)
void gat_kernel(const float* __restrict__ x, const float* __restrict__ aw,
                const _Float16* __restrict__ Wh, const _Float16* __restrict__ Wl,
                float* __restrict__ out) {
    extern __shared__ char smem[];
    const int b    = blockIdx.x;
    const int tid  = threadIdx.x;
    const int w    = tid >> 6;      // wave 0..7, owns output cols w*32..w*32+31
    const int lane = tid & 63;
    const int l15  = lane & 15;
    const int lq   = lane >> 4;

    // ---------------- stage x -> LDS f16 hi/lo (swizzled) -------------------
    const float* xb = x + (size_t)b * (MM * CC);
    {
        int r  = tid >> 3;           // row 0..63
        int g0 = tid & 7;
#pragma unroll
        for (int it = 0; it < 4; ++it) {
            int g8 = g0 + it * 8;    // 16B granule (8 f16) 0..31
            const float* src = xb + r * CC + g8 * 8;
            f32x4 v0 = *(const f32x4*)(src);
            f32x4 v1 = *(const f32x4*)(src + 4);
            h16x8 hv, lv;
#pragma unroll
            for (int e = 0; e < 4; ++e) {
                float f0 = v0[e], f1 = v1[e];
                _Float16 h0 = (_Float16)f0; hv[e]   = h0; lv[e]   = (_Float16)(f0 - (float)h0);
                _Float16 h1 = (_Float16)f1; hv[4+e] = h1; lv[4+e] = (_Float16)(f1 - (float)h1);
            }
            int byte = r * 512 + ((g8 ^ (r & 7)) * 16);
            *(h16x8*)(smem + XH + byte) = hv;
            *(h16x8*)(smem + XL + byte) = lv;
        }
    }

    // prefetch first W frags + attention weights (L2 latency under barrier)
    h16x8 Bh[2][2], Bl[2][2];
    float ai[2], aj[2];
#pragma unroll
    for (int nt = 0; nt < 2; ++nt) {
        int col = w * 32 + nt * 16 + l15;
        Bh[0][nt] = *(const h16x8*)(Wh + col * CC + lq * 8);
        Bl[0][nt] = *(const h16x8*)(Wl + col * CC + lq * 8);
        ai[nt] = aw[col];
        aj[nt] = aw[256 + col];
    }
    __syncthreads();

    // ---------------- matmul1: h = x @ W^T (cols n-partitioned, 8 waves) ----
    f32x4 acc[4][2] = {};
#pragma unroll
    for (int ks = 0; ks < 8; ++ks) {
        int cur = ks & 1, nxt = cur ^ 1;
        if (ks < 7) {
#pragma unroll
            for (int nt = 0; nt < 2; ++nt) {
                int col = w * 32 + nt * 16 + l15;
                Bh[nxt][nt] = *(const h16x8*)(Wh + col * CC + (ks + 1) * 32 + lq * 8);
                Bl[nxt][nt] = *(const h16x8*)(Wl + col * CC + (ks + 1) * 32 + lq * 8);
            }
        }
#pragma unroll
        for (int mt = 0; mt < 4; ++mt) {
            int r = mt * 16 + l15;
            int g = (((ks * 4 + lq) ^ (r & 7)) * 16);
            h16x8 Ah = *(const h16x8*)(smem + XH + r * 512 + g);
            h16x8 Al = *(const h16x8*)(smem + XL + r * 512 + g);
#pragma unroll
            for (int nt = 0; nt < 2; ++nt) {
                acc[mt][nt] = mfma16(Al, Bh[cur][nt], acc[mt][nt]);
                acc[mt][nt] = mfma16(Ah, Bl[cur][nt], acc[mt][nt]);
                acc[mt][nt] = mfma16(Ah, Bh[cur][nt], acc[mt][nt]);
            }
        }
    }

    // ---------------- s_i / s_j partials (per-wave, over its 32 cols) -------
    {
        float* sparti = (float*)(smem + SP_I);   // [8][64]
        float* spartj = (float*)(smem + SP_J);   // [8][64]
#pragma unroll
        for (int mt = 0; mt < 4; ++mt) {
#pragma unroll
            for (int rg = 0; rg < 4; ++rg) {
                float s1 = 0.f, s2 = 0.f;
#pragma unroll
                for (int nt = 0; nt < 2; ++nt) {
                    float v = acc[mt][nt][rg];
                    s1 += v * ai[nt];
                    s2 += v * aj[nt];
                }
                s1 += __shfl_xor(s1, 1);  s2 += __shfl_xor(s2, 1);
                s1 += __shfl_xor(s1, 2);  s2 += __shfl_xor(s2, 2);
                s1 += __shfl_xor(s1, 4);  s2 += __shfl_xor(s2, 4);
                s1 += __shfl_xor(s1, 8);  s2 += __shfl_xor(s2, 8);
                if (l15 == 0) {
                    int row = mt * 16 + lq * 4 + rg;
                    sparti[w * 64 + row] = s1;
                    spartj[w * 64 + row] = s2;
                }
            }
        }
    }
    __syncthreads();   // x reads done; s partials visible

    // ---------------- hT (hi/lo) over dead x buffer; reduce s ---------------
#pragma unroll
    for (int mt = 0; mt < 4; ++mt) {
#pragma unroll
        for (int nt = 0; nt < 2; ++nt) {
            h16x4 hh, ll;
#pragma unroll
            for (int rg = 0; rg < 4; ++rg) {
                float f = acc[mt][nt][rg];
                _Float16 h = (_Float16)f;
                hh[rg] = h;
                ll[rg] = (_Float16)(f - (float)h);
            }
            int c    = w * 32 + nt * 16 + l15;   // channel (hT row)
            int jb   = mt * 16 + lq * 4;         // node (hT col base)
            int byte = c * 128 + (((jb >> 3) ^ (c & 7)) * 16) + (jb & 7) * 2;
            *(h16x4*)(smem + XH + byte) = hh;
            *(h16x4*)(smem + XL + byte) = ll;
        }
    }
    if (tid < 128) {
        int row = tid & 63;
        const float* sp = (tid < 64) ? (const float*)(smem + SP_I)
                                     : (const float*)(smem + SP_J);
        float v = 0.f;
#pragma unroll
        for (int k = 0; k < 8; ++k) v += sp[k * 64 + row];
        float* dst = (tid < 64) ? (float*)(smem + SF_I) : (float*)(smem + SF_J);
        dst[row] = v;
    }
    __syncthreads();

    // ---------------- softmax over j (row i = w*8+(lane>>3), 8 lanes/row) ---
    {
        const float* sfini = (const float*)(smem + SF_I);
        const float* sfinj = (const float*)(smem + SF_J);
        int i  = w * 8 + (lane >> 3);
        int jc = (lane & 7) * 8;
        float siv = sfini[i];
        f32x4 sv0 = *(const f32x4*)(sfinj + jc);
        f32x4 sv1 = *(const f32x4*)(sfinj + jc + 4);
        float p[8];
        float mx = -1e30f;
#pragma unroll
        for (int e = 0; e < 4; ++e) {
            float e0 = siv + sv0[e]; e0 = e0 > 0.f ? e0 : 0.2f * e0;
            float e1 = siv + sv1[e]; e1 = e1 > 0.f ? e1 : 0.2f * e1;
            p[e] = e0; p[4 + e] = e1;
            mx = fmaxf(mx, fmaxf(e0, e1));
        }
        mx = fmaxf(mx, __shfl_xor(mx, 1));
        mx = fmaxf(mx, __shfl_xor(mx, 2));
        mx = fmaxf(mx, __shfl_xor(mx, 4));
        float sum = 0.f;
#pragma unroll
        for (int t = 0; t < 8; ++t) { p[t] = __expf(p[t] - mx); sum += p[t]; }
        sum += __shfl_xor(sum, 1);
        sum += __shfl_xor(sum, 2);
        sum += __shfl_xor(sum, 4);
        float inv = 1.0f / sum;
        __syncthreads();   // s-buffers dead; attn region may be overwritten
        h16x8 ph, pl;
#pragma unroll
        for (int t = 0; t < 8; ++t) {
            float f = p[t] * inv;
            _Float16 h = (_Float16)f;
            ph[t] = h;
            pl[t] = (_Float16)(f - (float)h);
        }
        int byte = i * 128 + (((lane & 7) ^ (i & 7)) * 16);
        *(h16x8*)(smem + AT  + byte) = ph;
        *(h16x8*)(smem + ATL + byte) = pl;
    }
    __syncthreads();

    // ---------------- matmul2: out = relu(attn @ h) -------------------------
    f32x4 acc2[4][2] = {};
#pragma unroll
    for (int ks = 0; ks < 2; ++ks) {
        h16x8 Ah2[4], Al2[4], Bh2[2], Bl2[2];
#pragma unroll
        for (int mt = 0; mt < 4; ++mt) {
            int i = mt * 16 + l15;
            int g = (((ks * 4 + lq) ^ (i & 7)) * 16);
            Ah2[mt] = *(const h16x8*)(smem + AT  + i * 128 + g);
            Al2[mt] = *(const h16x8*)(smem + ATL + i * 128 + g);
        }
#pragma unroll
        for (int nt = 0; nt < 2; ++nt) {
            int c = w * 32 + nt * 16 + l15;
            int g = (((ks * 4 + lq) ^ (c & 7)) * 16);
            Bh2[nt] = *(const h16x8*)(smem + XH + c * 128 + g);
            Bl2[nt] = *(const h16x8*)(smem + XL + c * 128 + g);
        }
#pragma unroll
        for (int mt = 0; mt < 4; ++mt) {
#pragma unroll
            for (int nt = 0; nt < 2; ++nt) {
                acc2[mt][nt] = mfma16(Al2[mt], Bh2[nt], acc2[mt][nt]);
                acc2[mt][nt] = mfma16(Ah2[mt], Bl2[nt], acc2[mt][nt]);
                acc2[mt][nt] = mfma16(Ah2[mt], Bh2[nt], acc2[mt][nt]);
            }
        }
    }
    __syncthreads();   // all hT/attn reads done; LDS free for out staging

    // ---------------- relu -> LDS (padded rows) -> coalesced b128 store -----
#pragma unroll
    for (int mt = 0; mt < 4; ++mt) {
#pragma unroll
        for (int nt = 0; nt < 2; ++nt) {
            int col = w * 32 + nt * 16 + l15;
#pragma unroll
            for (int rg = 0; rg < 4; ++rg) {
                int row = mt * 16 + lq * 4 + rg;
                *(float*)(smem + row * OSTR + col * 4) =
                    fmaxf(acc2[mt][nt][rg], 0.f);
            }
        }
    }
    __syncthreads();
    float* ob = out + (size_t)b * (MM * CC);
#pragma unroll
    for (int it = 0; it < 8; ++it) {
        int idx = it * 512 + tid;        // f32x4 index over [64][256]
        int row = idx >> 6;
        int c4  = idx & 63;
        f32x4 v = *(const f32x4*)(smem + row * OSTR + c4 * 16);
        *(f32x4*)(ob + idx * 4) = v;
    }
}

extern "C" void kernel_launch(void* const* d_in, const int* in_sizes, int n_in,
                              void* d_out, int out_size, void* d_ws, size_t ws_size,
                              hipStream_t stream) {
    (void)in_sizes; (void)n_in; (void)out_size; (void)ws_size;
    const float* x  = (const float*)d_in[0];
    const float* W  = (const float*)d_in[1];
    const float* aw = (const float*)d_in[2];
    float* out = (float*)d_out;

    _Float16* Wh = (_Float16*)d_ws;          // 65536 f16 = 128KB
    _Float16* Wl = Wh + 65536;               // another 128KB

    (void)hipFuncSetAttribute((const void*)gat_kernel,
                              hipFuncAttributeMaxDynamicSharedMemorySize, 81920);

    prep_w<<<64, 256, 0, stream>>>(W, Wh, Wl);
    gat_kernel<<<NB, 512, 81920, stream>>>(x, aw, Wh, Wl, out);
}